// Round 1
// baseline (1616.575 us; speedup 1.0000x reference)
//
#include <hip/hip_runtime.h>
#include <hip/hip_bf16.h>

// Problem: RandomProjectionQuantizer  B=4 N=4096 D=1024 E=512 K=4096
// M = B*N = 16384 rows.
// proj = X @ P (fp32), xn = normalize rows, cn = normalize codebook rows,
// nearest = argmin_k ( cnsq_k - 2*cn_k . xn_m )  [row-const terms dropped]
//         = argmax_k ( 2*invr_m*invc_k*(cb_k . proj_m) - cnsq_k ), ties -> min k.

#define M_ROWS 16384
#define D_DIM  1024
#define E_DIM  512
#define K_CB   4096
#define EPS_N  1e-12f

// ---------------------------------------------------------------- row norms
// One wave per row of 512 floats. Computes inv = 1/max(||v||,eps) and
// optionally sq = sum((v/max(||v||,eps))^2)  (the reference's cnsq).
__global__ __launch_bounds__(256) void row_norm_kernel(
    const float* __restrict__ src, float* __restrict__ inv_out,
    float* __restrict__ sq_out) {
  int row  = blockIdx.x * 4 + (threadIdx.x >> 6);
  int lane = threadIdx.x & 63;
  const float4* p = (const float4*)(src + (size_t)row * E_DIM);
  float4 v0 = p[lane];
  float4 v1 = p[lane + 64];
  float s = v0.x * v0.x + v0.y * v0.y + v0.z * v0.z + v0.w * v0.w +
            v1.x * v1.x + v1.y * v1.y + v1.z * v1.z + v1.w * v1.w;
#pragma unroll
  for (int m = 32; m; m >>= 1) s += __shfl_xor(s, m, 64);
  float d = fmaxf(sqrtf(s), EPS_N);
  if (sq_out) {
    float q0 = v0.x / d, q1 = v0.y / d, q2 = v0.z / d, q3 = v0.w / d;
    float q4 = v1.x / d, q5 = v1.y / d, q6 = v1.z / d, q7 = v1.w / d;
    float q = q0 * q0 + q1 * q1 + q2 * q2 + q3 * q3 +
              q4 * q4 + q5 * q5 + q6 * q6 + q7 * q7;
#pragma unroll
    for (int m = 32; m; m >>= 1) q += __shfl_xor(q, m, 64);
    if (lane == 0) sq_out[row] = q;
  }
  if (lane == 0) inv_out[row] = 1.0f / d;
}

// ---------------------------------------------------------------- GEMM1
// C(16384x512) = A(16384x1024) * B(1024x512).  128x128 tile, BK=16,
// 256 threads, 8x8 micro-tile, double-buffered LDS.
__global__ __launch_bounds__(256, 2) void gemm1_kernel(
    const float* __restrict__ A, const float* __restrict__ Bm,
    float* __restrict__ C) {
  __shared__ float As[2][16][132];  // [k][m], padded
  __shared__ float Bs[2][16][128];  // [k][n]
  int tid = threadIdx.x;
  int tx = tid & 15, ty = tid >> 4;  // 16x16 thread grid
  int n0 = blockIdx.x * 128;
  int m0 = blockIdx.y * 128;

  int arow = tid >> 2;            // 0..63
  int akq  = (tid & 3) * 4;       // 0,4,8,12
  int bk   = tid >> 5;            // 0..7
  int bcol = (tid & 31) * 4;      // 0..124

  const float* Aptr  = A + (size_t)(m0 + arow) * D_DIM + akq;
  const float* Aptr2 = Aptr + (size_t)64 * D_DIM;
  const float* Bptr  = Bm + (size_t)bk * E_DIM + n0 + bcol;
  const float* Bptr2 = Bptr + (size_t)8 * E_DIM;

  float acc[8][8] = {};

  float4 a0 = *(const float4*)(Aptr);
  float4 a1 = *(const float4*)(Aptr2);
  float4 b0 = *(const float4*)(Bptr);
  float4 b1 = *(const float4*)(Bptr2);

  int buf = 0;
  for (int k0 = 0; k0 < D_DIM; k0 += 16) {
    As[buf][akq + 0][arow] = a0.x;
    As[buf][akq + 1][arow] = a0.y;
    As[buf][akq + 2][arow] = a0.z;
    As[buf][akq + 3][arow] = a0.w;
    As[buf][akq + 0][arow + 64] = a1.x;
    As[buf][akq + 1][arow + 64] = a1.y;
    As[buf][akq + 2][arow + 64] = a1.z;
    As[buf][akq + 3][arow + 64] = a1.w;
    *(float4*)&Bs[buf][bk][bcol]     = b0;
    *(float4*)&Bs[buf][bk + 8][bcol] = b1;
    __syncthreads();
    if (k0 + 16 < D_DIM) {
      a0 = *(const float4*)(Aptr + k0 + 16);
      a1 = *(const float4*)(Aptr2 + k0 + 16);
      b0 = *(const float4*)(Bptr + (size_t)(k0 + 16) * E_DIM);
      b1 = *(const float4*)(Bptr2 + (size_t)(k0 + 16) * E_DIM);
    }
#pragma unroll
    for (int kk = 0; kk < 16; ++kk) {
      float4 av0 = *(const float4*)&As[buf][kk][ty * 8];
      float4 av1 = *(const float4*)&As[buf][kk][ty * 8 + 4];
      float4 bv0 = *(const float4*)&Bs[buf][kk][tx * 4];
      float4 bv1 = *(const float4*)&Bs[buf][kk][tx * 4 + 64];
      float a[8] = {av0.x, av0.y, av0.z, av0.w, av1.x, av1.y, av1.z, av1.w};
      float b[8] = {bv0.x, bv0.y, bv0.z, bv0.w, bv1.x, bv1.y, bv1.z, bv1.w};
#pragma unroll
      for (int i = 0; i < 8; ++i)
#pragma unroll
        for (int j = 0; j < 8; ++j) acc[i][j] = fmaf(a[i], b[j], acc[i][j]);
    }
    buf ^= 1;
  }

#pragma unroll
  for (int i = 0; i < 8; ++i) {
    float* crow = C + (size_t)(m0 + ty * 8 + i) * E_DIM + n0;
    *(float4*)(crow + tx * 4)      = make_float4(acc[i][0], acc[i][1], acc[i][2], acc[i][3]);
    *(float4*)(crow + tx * 4 + 64) = make_float4(acc[i][4], acc[i][5], acc[i][6], acc[i][7]);
  }
}

// ---------------------------------------------------------------- GEMM2+argmax
// Per block: 64 rows x 2048 codewords (codebook split in 2), full E=512.
// 256 threads, 8x8 micro-tile over a 64x256 score tile per n0 iteration.
__global__ __launch_bounds__(256, 2) void argmax_kernel(
    const float* __restrict__ P, const float* __restrict__ CB,
    const float* __restrict__ invr, const float* __restrict__ invc,
    const float* __restrict__ cnsq, float* __restrict__ cand_s,
    int* __restrict__ cand_i) {
  __shared__ float As[2][16][68];    // [k][m]
  __shared__ float Bs[2][16][256];   // [k][n]
  __shared__ float invr_s[64];
  __shared__ float red_s[64][33];
  __shared__ int   red_i[64][33];

  int tid = threadIdx.x;
  int tx = tid & 31, ty = tid >> 5;  // tx 0..31 (cols), ty 0..7 (rows)
  int m0 = blockIdx.x * 64;
  int cbase = blockIdx.y * 2048;

  if (tid < 64) invr_s[tid] = invr[m0 + tid];

  int arow = tid >> 2;          // 0..63
  int akq  = (tid & 3) * 4;     // 0,4,8,12
  const float* Aptr = P + (size_t)(m0 + arow) * E_DIM + akq;

  float best[8];
  int   bidx[8];
#pragma unroll
  for (int i = 0; i < 8; ++i) { best[i] = -3.4e38f; bidx[i] = 0; }

  for (int n0 = 0; n0 < 2048; n0 += 256) {
    const float* Bptr = CB + (size_t)(cbase + n0 + tid) * E_DIM;
    float4 a0 = *(const float4*)(Aptr);
    float4 b0 = *(const float4*)(Bptr + 0);
    float4 b1 = *(const float4*)(Bptr + 4);
    float4 b2 = *(const float4*)(Bptr + 8);
    float4 b3 = *(const float4*)(Bptr + 12);
    float acc[8][8] = {};
    int buf = 0;
    for (int k0 = 0; k0 < E_DIM; k0 += 16) {
      As[buf][akq + 0][arow] = a0.x;
      As[buf][akq + 1][arow] = a0.y;
      As[buf][akq + 2][arow] = a0.z;
      As[buf][akq + 3][arow] = a0.w;
      // thread t owns codeword column (n0+t): conflict-free (bank = t%32)
      Bs[buf][0][tid] = b0.x;  Bs[buf][1][tid] = b0.y;
      Bs[buf][2][tid] = b0.z;  Bs[buf][3][tid] = b0.w;
      Bs[buf][4][tid] = b1.x;  Bs[buf][5][tid] = b1.y;
      Bs[buf][6][tid] = b1.z;  Bs[buf][7][tid] = b1.w;
      Bs[buf][8][tid] = b2.x;  Bs[buf][9][tid] = b2.y;
      Bs[buf][10][tid] = b2.z; Bs[buf][11][tid] = b2.w;
      Bs[buf][12][tid] = b3.x; Bs[buf][13][tid] = b3.y;
      Bs[buf][14][tid] = b3.z; Bs[buf][15][tid] = b3.w;
      __syncthreads();
      if (k0 + 16 < E_DIM) {
        a0 = *(const float4*)(Aptr + k0 + 16);
        b0 = *(const float4*)(Bptr + k0 + 16);
        b1 = *(const float4*)(Bptr + k0 + 20);
        b2 = *(const float4*)(Bptr + k0 + 24);
        b3 = *(const float4*)(Bptr + k0 + 28);
      }
#pragma unroll
      for (int kk = 0; kk < 16; ++kk) {
        float4 av0 = *(const float4*)&As[buf][kk][ty * 8];
        float4 av1 = *(const float4*)&As[buf][kk][ty * 8 + 4];
        float4 bv0 = *(const float4*)&Bs[buf][kk][tx * 4];
        float4 bv1 = *(const float4*)&Bs[buf][kk][tx * 4 + 128];
        float a[8] = {av0.x, av0.y, av0.z, av0.w, av1.x, av1.y, av1.z, av1.w};
        float b[8] = {bv0.x, bv0.y, bv0.z, bv0.w, bv1.x, bv1.y, bv1.z, bv1.w};
#pragma unroll
        for (int i = 0; i < 8; ++i)
#pragma unroll
          for (int j = 0; j < 8; ++j) acc[i][j] = fmaf(a[i], b[j], acc[i][j]);
      }
      buf ^= 1;
    }
    // epilogue for this 256-codeword tile: scores + running argmax.
    // Column order per thread is ascending (j4 then jj), n0 ascending,
    // strict '>' keeps the FIRST max -> matches argmin first-occurrence.
#pragma unroll
    for (int j4 = 0; j4 < 2; ++j4) {
      int nb = cbase + n0 + j4 * 128 + tx * 4;
      float4 ic = *(const float4*)&invc[nb];
      float4 cq = *(const float4*)&cnsq[nb];
      float icv[4] = {ic.x, ic.y, ic.z, ic.w};
      float cqv[4] = {cq.x, cq.y, cq.z, cq.w};
#pragma unroll
      for (int i = 0; i < 8; ++i) {
        float ir2 = 2.0f * invr_s[ty * 8 + i];
#pragma unroll
        for (int jj = 0; jj < 4; ++jj) {
          float sc = acc[i][j4 * 4 + jj] * ir2 * icv[jj] - cqv[jj];
          if (sc > best[i]) { best[i] = sc; bidx[i] = nb + jj; }
        }
      }
    }
  }

  // cross-thread (tx) reduction per row
  __syncthreads();
#pragma unroll
  for (int i = 0; i < 8; ++i) {
    red_s[ty * 8 + i][tx] = best[i];
    red_i[ty * 8 + i][tx] = bidx[i];
  }
  __syncthreads();
  if (tid < 64) {
    float bs = red_s[tid][0];
    int bi = red_i[tid][0];
#pragma unroll
    for (int t = 1; t < 32; ++t) {
      float s = red_s[tid][t];
      int ii = red_i[tid][t];
      if (s > bs || (s == bs && ii < bi)) { bs = s; bi = ii; }
    }
    cand_s[(size_t)(m0 + tid) * 2 + blockIdx.y] = bs;
    cand_i[(size_t)(m0 + tid) * 2 + blockIdx.y] = bi;
  }
}

// ---------------------------------------------------------------- combine
__global__ __launch_bounds__(256) void combine_kernel(
    const float* __restrict__ cand_s, const int* __restrict__ cand_i,
    int* __restrict__ out) {
  int r = blockIdx.x * 256 + threadIdx.x;
  float s0 = cand_s[r * 2], s1 = cand_s[r * 2 + 1];
  int i0 = cand_i[r * 2], i1 = cand_i[r * 2 + 1];
  out[r] = (s1 > s0 || (s1 == s0 && i1 < i0)) ? i1 : i0;
}

// ---------------------------------------------------------------- launch
extern "C" void kernel_launch(void* const* d_in, const int* in_sizes, int n_in,
                              void* d_out, int out_size, void* d_ws, size_t ws_size,
                              hipStream_t stream) {
  const float* x  = (const float*)d_in[0];   // (4,4096,1024)
  const float* rp = (const float*)d_in[1];   // (1024,512)
  const float* cb = (const float*)d_in[2];   // (4096,512)
  int* out = (int*)d_out;                    // (4,4096) int32

  float* ws    = (float*)d_ws;
  float* proj  = ws;                                   // 16384*512
  float* invr  = proj + (size_t)M_ROWS * E_DIM;        // 16384
  float* invc  = invr + M_ROWS;                        // 4096
  float* cnsq  = invc + K_CB;                          // 4096
  float* cands = cnsq + K_CB;                          // 16384*2
  int*   candi = (int*)(cands + (size_t)M_ROWS * 2);   // 16384*2

  row_norm_kernel<<<K_CB / 4, 256, 0, stream>>>(cb, invc, cnsq);
  gemm1_kernel<<<dim3(E_DIM / 128, M_ROWS / 128), 256, 0, stream>>>(x, rp, proj);
  row_norm_kernel<<<M_ROWS / 4, 256, 0, stream>>>(proj, invr, nullptr);
  argmax_kernel<<<dim3(M_ROWS / 64, 2), 256, 0, stream>>>(proj, cb, invr, invc,
                                                          cnsq, cands, candi);
  combine_kernel<<<M_ROWS / 256, 256, 0, stream>>>(cands, candi, out);
}

// Round 3
// 1024.354 us; speedup vs baseline: 1.5781x; 1.5781x over previous
//
#include <hip/hip_runtime.h>
#include <hip/hip_bf16.h>

// Problem: RandomProjectionQuantizer  B=4 N=4096 D=1024 E=512 K=4096
// M = B*N = 16384 rows.
// proj = X @ P (fp32), scores = 2*invr_m*invc_k*(cb_k . proj_m) - cnsq_k,
// nearest = argmax_k score (ties -> min k).
// Round 3: fix wn-race (LDS merge of the two column-half waves) and use
// known-safe load+ds_write staging instead of global_load_lds.

#define M_ROWS 16384
#define D_DIM  1024
#define E_DIM  512
#define K_CB   4096
#define EPS_N  1e-12f
#define TAU_FIX 1e-4f
#define NEG_INF (-3.4e38f)

typedef short bf16x8 __attribute__((ext_vector_type(8)));
typedef float f32x4  __attribute__((ext_vector_type(4)));

// ---------------------------------------------------------------- helpers
__device__ __forceinline__ unsigned short f32_to_bf16_rtne(float x) {
  unsigned u = __float_as_uint(x);
  unsigned r = u + 0x7FFFu + ((u >> 16) & 1u);
  return (unsigned short)(r >> 16);
}
__device__ __forceinline__ float bf16_bits_to_f32(unsigned short h) {
  return __uint_as_float(((unsigned)h) << 16);
}

// ---------------------------------------------------------------- row norms
__global__ __launch_bounds__(256) void row_norm_kernel(
    const float* __restrict__ src, float* __restrict__ inv_out,
    float* __restrict__ sq_out) {
  int row  = blockIdx.x * 4 + (threadIdx.x >> 6);
  int lane = threadIdx.x & 63;
  const float4* p = (const float4*)(src + (size_t)row * E_DIM);
  float4 v0 = p[lane];
  float4 v1 = p[lane + 64];
  float s = v0.x * v0.x + v0.y * v0.y + v0.z * v0.z + v0.w * v0.w +
            v1.x * v1.x + v1.y * v1.y + v1.z * v1.z + v1.w * v1.w;
#pragma unroll
  for (int m = 32; m; m >>= 1) s += __shfl_xor(s, m, 64);
  float d = fmaxf(sqrtf(s), EPS_N);
  if (sq_out) {
    float q0 = v0.x / d, q1 = v0.y / d, q2 = v0.z / d, q3 = v0.w / d;
    float q4 = v1.x / d, q5 = v1.y / d, q6 = v1.z / d, q7 = v1.w / d;
    float q = q0 * q0 + q1 * q1 + q2 * q2 + q3 * q3 +
              q4 * q4 + q5 * q5 + q6 * q6 + q7 * q7;
#pragma unroll
    for (int m = 32; m; m >>= 1) q += __shfl_xor(q, m, 64);
    if (lane == 0) sq_out[row] = q;
  }
  if (lane == 0) inv_out[row] = 1.0f / d;
}

// ---------------------------------------------------------------- GEMM1 (fp32)
__global__ __launch_bounds__(256, 2) void gemm1_kernel(
    const float* __restrict__ A, const float* __restrict__ Bm,
    float* __restrict__ C) {
  __shared__ float As[2][16][132];
  __shared__ float Bs[2][16][128];
  int tid = threadIdx.x;
  int tx = tid & 15, ty = tid >> 4;
  int n0 = blockIdx.x * 128;
  int m0 = blockIdx.y * 128;

  int arow = tid >> 2;
  int akq  = (tid & 3) * 4;
  int bk   = tid >> 5;
  int bcol = (tid & 31) * 4;

  const float* Aptr  = A + (size_t)(m0 + arow) * D_DIM + akq;
  const float* Aptr2 = Aptr + (size_t)64 * D_DIM;
  const float* Bptr  = Bm + (size_t)bk * E_DIM + n0 + bcol;
  const float* Bptr2 = Bptr + (size_t)8 * E_DIM;

  float acc[8][8] = {};
  float4 a0 = *(const float4*)(Aptr);
  float4 a1 = *(const float4*)(Aptr2);
  float4 b0 = *(const float4*)(Bptr);
  float4 b1 = *(const float4*)(Bptr2);

  int buf = 0;
  for (int k0 = 0; k0 < D_DIM; k0 += 16) {
    As[buf][akq + 0][arow] = a0.x;
    As[buf][akq + 1][arow] = a0.y;
    As[buf][akq + 2][arow] = a0.z;
    As[buf][akq + 3][arow] = a0.w;
    As[buf][akq + 0][arow + 64] = a1.x;
    As[buf][akq + 1][arow + 64] = a1.y;
    As[buf][akq + 2][arow + 64] = a1.z;
    As[buf][akq + 3][arow + 64] = a1.w;
    *(float4*)&Bs[buf][bk][bcol]     = b0;
    *(float4*)&Bs[buf][bk + 8][bcol] = b1;
    __syncthreads();
    if (k0 + 16 < D_DIM) {
      a0 = *(const float4*)(Aptr + k0 + 16);
      a1 = *(const float4*)(Aptr2 + k0 + 16);
      b0 = *(const float4*)(Bptr + (size_t)(k0 + 16) * E_DIM);
      b1 = *(const float4*)(Bptr2 + (size_t)(k0 + 16) * E_DIM);
    }
#pragma unroll
    for (int kk = 0; kk < 16; ++kk) {
      float4 av0 = *(const float4*)&As[buf][kk][ty * 8];
      float4 av1 = *(const float4*)&As[buf][kk][ty * 8 + 4];
      float4 bv0 = *(const float4*)&Bs[buf][kk][tx * 4];
      float4 bv1 = *(const float4*)&Bs[buf][kk][tx * 4 + 64];
      float a[8] = {av0.x, av0.y, av0.z, av0.w, av1.x, av1.y, av1.z, av1.w};
      float b[8] = {bv0.x, bv0.y, bv0.z, bv0.w, bv1.x, bv1.y, bv1.z, bv1.w};
#pragma unroll
      for (int i = 0; i < 8; ++i)
#pragma unroll
        for (int j = 0; j < 8; ++j) acc[i][j] = fmaf(a[i], b[j], acc[i][j]);
    }
    buf ^= 1;
  }
#pragma unroll
  for (int i = 0; i < 8; ++i) {
    float* crow = C + (size_t)(m0 + ty * 8 + i) * E_DIM + n0;
    *(float4*)(crow + tx * 4)      = make_float4(acc[i][0], acc[i][1], acc[i][2], acc[i][3]);
    *(float4*)(crow + tx * 4 + 64) = make_float4(acc[i][4], acc[i][5], acc[i][6], acc[i][7]);
  }
}

// ---------------------------------------------------------------- split+permute
// src (rows x 512 fp32) -> hi/lo bf16 in MFMA staging order:
// out[(rb*16+kc)*512 + q*128 + row][j] = bf16(src[rb*128+row][kc*32+q*8+j])
__global__ __launch_bounds__(256) void split_permute_kernel(
    const float* __restrict__ src, short* __restrict__ hi,
    short* __restrict__ lo) {
  int rb = blockIdx.x, kc = blockIdx.y;
  int tid = threadIdx.x;
  for (int c = tid; c < 512; c += 256) {
    int q = c >> 7, row = c & 127;
    const float* s = src + (size_t)(rb * 128 + row) * E_DIM + kc * 32 + q * 8;
    float4 f0 = *(const float4*)s;
    float4 f1 = *(const float4*)(s + 4);
    float v[8] = {f0.x, f0.y, f0.z, f0.w, f1.x, f1.y, f1.z, f1.w};
    union { short s8[8]; float4 f; } H, L;
#pragma unroll
    for (int j = 0; j < 8; ++j) {
      unsigned short h = f32_to_bf16_rtne(v[j]);
      float hf = bf16_bits_to_f32(h);
      unsigned short l = f32_to_bf16_rtne(v[j] - hf);
      H.s8[j] = (short)h;
      L.s8[j] = (short)l;
    }
    size_t off = ((size_t)(rb * 16 + kc) * 512 + c) * 8;
    *(float4*)(hi + off) = H.f;
    *(float4*)(lo + off) = L.f;
  }
}

// ---------------------------------------------------------------- MFMA argmax
// grid (128 mblocks, 32 nblocks), 256 thr = 4 waves (2x2 over 128x128 tile),
// wave tile 64x64, 4x4 fragments of 16x16x32 bf16, 3 MFMA per fragment pair.
__global__ __launch_bounds__(256) void mfma_argmax_kernel(
    const short* __restrict__ Ah, const short* __restrict__ Al,
    const short* __restrict__ Bh, const short* __restrict__ Bl,
    const float* __restrict__ invr, const float* __restrict__ invc,
    const float* __restrict__ cnsq, float* __restrict__ candb,
    float* __restrict__ cands2, int* __restrict__ candi) {
  __shared__ float ldsf[8192];  // 32 KB: Ah|Al|Bh|Bl regions of 8 KB each
  char* lds = (char*)ldsf;
  int tid = threadIdx.x;
  int wid = tid >> 6, lane = tid & 63;
  int mb = blockIdx.x, nb = blockIdx.y;
  int wm = wid >> 1, wn = wid & 1;
  int q = lane >> 4, c0 = lane & 15;

  f32x4 zero = {0.f, 0.f, 0.f, 0.f};
  f32x4 acc[4][4];
#pragma unroll
  for (int i = 0; i < 4; ++i)
#pragma unroll
    for (int j = 0; j < 4; ++j) acc[i][j] = zero;

  for (int kc = 0; kc < 16; ++kc) {
    const char* ga[4] = {
        (const char*)Ah + ((size_t)(mb * 16 + kc)) * 8192,
        (const char*)Al + ((size_t)(mb * 16 + kc)) * 8192,
        (const char*)Bh + ((size_t)(nb * 16 + kc)) * 8192,
        (const char*)Bl + ((size_t)(nb * 16 + kc)) * 8192};
    // stage 32 KB: 8 passes x (256 thr x 16 B). coalesced loads, b128 writes.
#pragma unroll
    for (int p = 0; p < 8; ++p) {
      int t = p >> 1;
      int ro = ((p & 1) << 12) | (tid << 4);
      *(float4*)(lds + t * 8192 + ro) = *(const float4*)(ga[t] + ro);
    }
    __syncthreads();

    bf16x8 ah[4], al[4], bh[4], bl[4];
#pragma unroll
    for (int mi = 0; mi < 4; ++mi) {
      int boff = (q * 128 + wm * 64 + mi * 16 + c0) << 4;
      ah[mi] = *(const bf16x8*)(lds + boff);
      al[mi] = *(const bf16x8*)(lds + 8192 + boff);
    }
#pragma unroll
    for (int ni = 0; ni < 4; ++ni) {
      int boff = (q * 128 + wn * 64 + ni * 16 + c0) << 4;
      bh[ni] = *(const bf16x8*)(lds + 16384 + boff);
      bl[ni] = *(const bf16x8*)(lds + 24576 + boff);
    }
#pragma unroll
    for (int mi = 0; mi < 4; ++mi) {
#pragma unroll
      for (int ni = 0; ni < 4; ++ni) {
        acc[mi][ni] = __builtin_amdgcn_mfma_f32_16x16x32_bf16(
            ah[mi], bh[ni], acc[mi][ni], 0, 0, 0);
        acc[mi][ni] = __builtin_amdgcn_mfma_f32_16x16x32_bf16(
            ah[mi], bl[ni], acc[mi][ni], 0, 0, 0);
        acc[mi][ni] = __builtin_amdgcn_mfma_f32_16x16x32_bf16(
            al[mi], bh[ni], acc[mi][ni], 0, 0, 0);
      }
    }
    __syncthreads();
  }

  // epilogue: per-wave top-2 over its 64 columns, then LDS merge of the two
  // column-half (wn) waves.  LDS staging region is dead now; overlay it.
  float* msb = ldsf;             // [2][128] best
  float* mss = ldsf + 256;       // [2][128] second
  int*   msi = (int*)(ldsf + 512);  // [2][128] best idx

  float icv[4], cqv[4];
#pragma unroll
  for (int ni = 0; ni < 4; ++ni) {
    int n = nb * 128 + wn * 64 + ni * 16 + c0;
    icv[ni] = invc[n];
    cqv[ni] = cnsq[n];
  }
#pragma unroll
  for (int mi = 0; mi < 4; ++mi) {
    float4 ir4 = *(const float4*)&invr[mb * 128 + wm * 64 + mi * 16 + q * 4];
    float irv[4] = {ir4.x, ir4.y, ir4.z, ir4.w};
#pragma unroll
    for (int r = 0; r < 4; ++r) {
      float tir = 2.0f * irv[r];
      float b = NEG_INF, s = NEG_INF;
      int bi = 2147483647;
#pragma unroll
      for (int ni = 0; ni < 4; ++ni) {
        float v = acc[mi][ni][r] * tir * icv[ni] - cqv[ni];
        int n = nb * 128 + wn * 64 + ni * 16 + c0;
        if (v > b) { s = b; b = v; bi = n; } else { s = fmaxf(s, v); }
      }
#pragma unroll
      for (int off = 1; off < 16; off <<= 1) {
        float ob = __shfl_xor(b, off, 64);
        float os = __shfl_xor(s, off, 64);
        int   oi = __shfl_xor(bi, off, 64);
        if (ob > b || (ob == b && oi < bi)) {
          s = fmaxf(b, os); b = ob; bi = oi;
        } else {
          s = fmaxf(s, ob);
        }
      }
      if (c0 == 0) {
        int rl = wm * 64 + mi * 16 + q * 4 + r;  // 0..127 within block
        msb[wn * 128 + rl] = b;
        mss[wn * 128 + rl] = s;
        msi[wn * 128 + rl] = bi;
      }
    }
  }
  __syncthreads();
  if (tid < 128) {
    float b0 = msb[tid],      s0 = mss[tid];
    float b1 = msb[128 + tid], s1 = mss[128 + tid];
    int   i0 = msi[tid],      i1 = msi[128 + tid];
    float B, S; int I;
    if (b1 > b0 || (b1 == b0 && i1 < i0)) {
      B = b1; S = fmaxf(s1, b0); I = i1;
    } else {
      B = b0; S = fmaxf(s0, b1); I = i0;
    }
    size_t o = (size_t)(mb * 128 + tid) * 32 + nb;
    candb[o] = B; cands2[o] = S; candi[o] = I;
  }
}

// ---------------------------------------------------------------- combine
__global__ __launch_bounds__(256) void combine2_kernel(
    const float* __restrict__ candb, const float* __restrict__ cands2,
    const int* __restrict__ candi, int* __restrict__ out,
    int* __restrict__ fixlist, int* __restrict__ fixcount) {
  int r = blockIdx.x * 256 + threadIdx.x;
  float b = NEG_INF, s = NEG_INF;
  int bi = 2147483647;
  const float* pb = candb + (size_t)r * 32;
  const float* ps = cands2 + (size_t)r * 32;
  const int*   pi = candi + (size_t)r * 32;
#pragma unroll 4
  for (int j = 0; j < 32; ++j) {
    float cb_ = pb[j], cs_ = ps[j];
    int ci_ = pi[j];
    if (cb_ > b || (cb_ == b && ci_ < bi)) {
      s = fmaxf(b, cs_); b = cb_; bi = ci_;
    } else {
      s = fmaxf(s, cb_);
    }
  }
  out[r] = bi;
  if (b - s < TAU_FIX) {
    int p = atomicAdd(fixcount, 1);
    if (p < M_ROWS) fixlist[p] = r;
  }
}

// ---------------------------------------------------------------- fixup (exact fp32)
__global__ __launch_bounds__(256) void fixup_kernel(
    const float* __restrict__ proj, const float* __restrict__ cb,
    const float* __restrict__ invr, const float* __restrict__ invc,
    const float* __restrict__ cnsq, const int* __restrict__ fixlist,
    const int* __restrict__ fixcount, int* __restrict__ out) {
  __shared__ float prow[E_DIM];
  __shared__ float wbest[4];
  __shared__ int   widx[4];
  int tid = threadIdx.x, wid = tid >> 6, lane = tid & 63;
  int n = *fixcount;
  if (n > M_ROWS) n = M_ROWS;
  for (int it = blockIdx.x; it < n; it += gridDim.x) {
    int r = fixlist[it];
    __syncthreads();
    for (int i = tid; i < E_DIM; i += 256) prow[i] = proj[(size_t)r * E_DIM + i];
    __syncthreads();
    float tir = 2.0f * invr[r];
    float best = NEG_INF;
    int bidx = 2147483647;
    for (int k = wid; k < K_CB; k += 4) {
      const float* cr = cb + (size_t)k * E_DIM + lane * 8;
      const float* pr = prow + lane * 8;
      float d = 0.f;
#pragma unroll
      for (int j = 0; j < 8; ++j) d = fmaf(cr[j], pr[j], d);
#pragma unroll
      for (int m = 1; m < 64; m <<= 1) d += __shfl_xor(d, m, 64);
      float sc = tir * invc[k] * d - cnsq[k];
      if (sc > best) { best = sc; bidx = k; }
    }
    if (lane == 0) { wbest[wid] = best; widx[wid] = bidx; }
    __syncthreads();
    if (tid == 0) {
      float b = wbest[0];
      int bi = widx[0];
#pragma unroll
      for (int w = 1; w < 4; ++w) {
        if (wbest[w] > b || (wbest[w] == b && widx[w] < bi)) {
          b = wbest[w]; bi = widx[w];
        }
      }
      out[r] = bi;
    }
  }
}

__global__ void zero_kernel(int* p) {
  if (threadIdx.x == 0 && blockIdx.x == 0) *p = 0;
}

// ================================================================ round-1
// fallback path (used only if ws_size is too small for the MFMA path)
__global__ __launch_bounds__(256, 2) void argmax_kernel(
    const float* __restrict__ P, const float* __restrict__ CB,
    const float* __restrict__ invr, const float* __restrict__ invc,
    const float* __restrict__ cnsq, float* __restrict__ cand_s,
    int* __restrict__ cand_i) {
  __shared__ float As[2][16][68];
  __shared__ float Bs[2][16][256];
  __shared__ float invr_s[64];
  __shared__ float red_s[64][33];
  __shared__ int   red_i[64][33];

  int tid = threadIdx.x;
  int tx = tid & 31, ty = tid >> 5;
  int m0 = blockIdx.x * 64;
  int cbase = blockIdx.y * 2048;
  if (tid < 64) invr_s[tid] = invr[m0 + tid];
  int arow = tid >> 2;
  int akq  = (tid & 3) * 4;
  const float* Aptr = P + (size_t)(m0 + arow) * E_DIM + akq;

  float best[8];
  int   bidx[8];
#pragma unroll
  for (int i = 0; i < 8; ++i) { best[i] = NEG_INF; bidx[i] = 0; }

  for (int n0 = 0; n0 < 2048; n0 += 256) {
    const float* Bptr = CB + (size_t)(cbase + n0 + tid) * E_DIM;
    float4 a0 = *(const float4*)(Aptr);
    float4 b0 = *(const float4*)(Bptr + 0);
    float4 b1 = *(const float4*)(Bptr + 4);
    float4 b2 = *(const float4*)(Bptr + 8);
    float4 b3 = *(const float4*)(Bptr + 12);
    float acc[8][8] = {};
    int buf = 0;
    for (int k0 = 0; k0 < E_DIM; k0 += 16) {
      As[buf][akq + 0][arow] = a0.x;
      As[buf][akq + 1][arow] = a0.y;
      As[buf][akq + 2][arow] = a0.z;
      As[buf][akq + 3][arow] = a0.w;
      Bs[buf][0][tid] = b0.x;  Bs[buf][1][tid] = b0.y;
      Bs[buf][2][tid] = b0.z;  Bs[buf][3][tid] = b0.w;
      Bs[buf][4][tid] = b1.x;  Bs[buf][5][tid] = b1.y;
      Bs[buf][6][tid] = b1.z;  Bs[buf][7][tid] = b1.w;
      Bs[buf][8][tid] = b2.x;  Bs[buf][9][tid] = b2.y;
      Bs[buf][10][tid] = b2.z; Bs[buf][11][tid] = b2.w;
      Bs[buf][12][tid] = b3.x; Bs[buf][13][tid] = b3.y;
      Bs[buf][14][tid] = b3.z; Bs[buf][15][tid] = b3.w;
      __syncthreads();
      if (k0 + 16 < E_DIM) {
        a0 = *(const float4*)(Aptr + k0 + 16);
        b0 = *(const float4*)(Bptr + k0 + 16);
        b1 = *(const float4*)(Bptr + k0 + 20);
        b2 = *(const float4*)(Bptr + k0 + 24);
        b3 = *(const float4*)(Bptr + k0 + 28);
      }
#pragma unroll
      for (int kk = 0; kk < 16; ++kk) {
        float4 av0 = *(const float4*)&As[buf][kk][ty * 8];
        float4 av1 = *(const float4*)&As[buf][kk][ty * 8 + 4];
        float4 bv0 = *(const float4*)&Bs[buf][kk][tx * 4];
        float4 bv1 = *(const float4*)&Bs[buf][kk][tx * 4 + 128];
        float a[8] = {av0.x, av0.y, av0.z, av0.w, av1.x, av1.y, av1.z, av1.w};
        float b[8] = {bv0.x, bv0.y, bv0.z, bv0.w, bv1.x, bv1.y, bv1.z, bv1.w};
#pragma unroll
        for (int i = 0; i < 8; ++i)
#pragma unroll
          for (int j = 0; j < 8; ++j) acc[i][j] = fmaf(a[i], b[j], acc[i][j]);
      }
      buf ^= 1;
    }
#pragma unroll
    for (int j4 = 0; j4 < 2; ++j4) {
      int nbq = cbase + n0 + j4 * 128 + tx * 4;
      float4 ic = *(const float4*)&invc[nbq];
      float4 cq = *(const float4*)&cnsq[nbq];
      float icv[4] = {ic.x, ic.y, ic.z, ic.w};
      float cqv[4] = {cq.x, cq.y, cq.z, cq.w};
#pragma unroll
      for (int i = 0; i < 8; ++i) {
        float ir2 = 2.0f * invr_s[ty * 8 + i];
#pragma unroll
        for (int jj = 0; jj < 4; ++jj) {
          float sc = acc[i][j4 * 4 + jj] * ir2 * icv[jj] - cqv[jj];
          if (sc > best[i]) { best[i] = sc; bidx[i] = nbq + jj; }
        }
      }
    }
  }
  __syncthreads();
#pragma unroll
  for (int i = 0; i < 8; ++i) {
    red_s[ty * 8 + i][tx] = best[i];
    red_i[ty * 8 + i][tx] = bidx[i];
  }
  __syncthreads();
  if (tid < 64) {
    float bs = red_s[tid][0];
    int bi = red_i[tid][0];
#pragma unroll
    for (int t = 1; t < 32; ++t) {
      float s = red_s[tid][t];
      int ii = red_i[tid][t];
      if (s > bs || (s == bs && ii < bi)) { bs = s; bi = ii; }
    }
    cand_s[(size_t)(m0 + tid) * 2 + blockIdx.y] = bs;
    cand_i[(size_t)(m0 + tid) * 2 + blockIdx.y] = bi;
  }
}

__global__ __launch_bounds__(256) void combine_kernel(
    const float* __restrict__ cand_s, const int* __restrict__ cand_i,
    int* __restrict__ out) {
  int r = blockIdx.x * 256 + threadIdx.x;
  float s0 = cand_s[r * 2], s1 = cand_s[r * 2 + 1];
  int i0 = cand_i[r * 2], i1 = cand_i[r * 2 + 1];
  out[r] = (s1 > s0 || (s1 == s0 && i1 < i0)) ? i1 : i0;
}

// ---------------------------------------------------------------- launch
extern "C" void kernel_launch(void* const* d_in, const int* in_sizes, int n_in,
                              void* d_out, int out_size, void* d_ws, size_t ws_size,
                              hipStream_t stream) {
  const float* x  = (const float*)d_in[0];
  const float* rp = (const float*)d_in[1];
  const float* cb = (const float*)d_in[2];
  int* out = (int*)d_out;

  // MFMA-path workspace layout
  char* w = (char*)d_ws;
  float* proj = (float*)w;      w += (size_t)M_ROWS * E_DIM * 4;   // 32 MB
  short* Ah   = (short*)w;      w += (size_t)M_ROWS * E_DIM * 2;   // 16 MB
  short* Al   = (short*)w;      w += (size_t)M_ROWS * E_DIM * 2;   // 16 MB
  short* Bh   = (short*)w;      w += (size_t)K_CB * E_DIM * 2;     // 4 MB
  short* Bl   = (short*)w;      w += (size_t)K_CB * E_DIM * 2;     // 4 MB
  float* invr = (float*)w;      w += M_ROWS * 4;
  float* invc = (float*)w;      w += K_CB * 4;
  float* cnsq = (float*)w;      w += K_CB * 4;
  float* candb  = (float*)w;    w += (size_t)M_ROWS * 32 * 4;      // 2 MB
  float* cands2 = (float*)w;    w += (size_t)M_ROWS * 32 * 4;      // 2 MB
  int*   candi  = (int*)w;      w += (size_t)M_ROWS * 32 * 4;      // 2 MB
  int*   fixlist  = (int*)w;    w += M_ROWS * 4;
  int*   fixcount = (int*)w;    w += 64;
  size_t need = (size_t)(w - (char*)d_ws);

  if (ws_size >= need) {
    zero_kernel<<<1, 64, 0, stream>>>(fixcount);
    row_norm_kernel<<<K_CB / 4, 256, 0, stream>>>(cb, invc, cnsq);
    gemm1_kernel<<<dim3(E_DIM / 128, M_ROWS / 128), 256, 0, stream>>>(x, rp, proj);
    row_norm_kernel<<<M_ROWS / 4, 256, 0, stream>>>(proj, invr, nullptr);
    split_permute_kernel<<<dim3(M_ROWS / 128, 16), 256, 0, stream>>>(proj, Ah, Al);
    split_permute_kernel<<<dim3(K_CB / 128, 16), 256, 0, stream>>>(cb, Bh, Bl);
    mfma_argmax_kernel<<<dim3(M_ROWS / 128, K_CB / 128), 256, 0, stream>>>(
        Ah, Al, Bh, Bl, invr, invc, cnsq, candb, cands2, candi);
    combine2_kernel<<<M_ROWS / 256, 256, 0, stream>>>(candb, cands2, candi, out,
                                                      fixlist, fixcount);
    fixup_kernel<<<256, 256, 0, stream>>>(proj, cb, invr, invc, cnsq, fixlist,
                                          fixcount, out);
  } else {
    // round-1 fallback (fits in ~35 MB)
    float* ws    = (float*)d_ws;
    float* proj1 = ws;
    float* invr1 = proj1 + (size_t)M_ROWS * E_DIM;
    float* invc1 = invr1 + M_ROWS;
    float* cnsq1 = invc1 + K_CB;
    float* cands = cnsq1 + K_CB;
    int*   candi1 = (int*)(cands + (size_t)M_ROWS * 2);

    row_norm_kernel<<<K_CB / 4, 256, 0, stream>>>(cb, invc1, cnsq1);
    gemm1_kernel<<<dim3(E_DIM / 128, M_ROWS / 128), 256, 0, stream>>>(x, rp, proj1);
    row_norm_kernel<<<M_ROWS / 4, 256, 0, stream>>>(proj1, invr1, nullptr);
    argmax_kernel<<<dim3(M_ROWS / 64, 2), 256, 0, stream>>>(proj1, cb, invr1,
                                                            invc1, cnsq1, cands, candi1);
    combine_kernel<<<M_ROWS / 256, 256, 0, stream>>>(cands, candi1, out);
  }
}